// Round 1
// baseline (681.570 us; speedup 1.0000x reference)
//
#include <hip/hip_runtime.h>

#define M_BATCH 16384
#define N_DIM   2048
#define K_DIM   2048

typedef __attribute__((ext_vector_type(8))) short bf16x8;   // 8 bf16 = 4 VGPRs
typedef __attribute__((ext_vector_type(4))) float f32x4;

// ---------- fp32 -> bf16 (RNE) conversion, 8 elements/thread ----------
__device__ __forceinline__ unsigned short f2bf_rne(float f) {
    union { float f; unsigned int u; } v; v.f = f;
    unsigned int r = v.u + 0x7fffu + ((v.u >> 16) & 1u);
    return (unsigned short)(r >> 16);
}

__global__ __launch_bounds__(256) void cvt_f32_bf16_x8(
        const float* __restrict__ src, unsigned short* __restrict__ dst, int n8) {
    int i = blockIdx.x * blockDim.x + threadIdx.x;
    if (i >= n8) return;
    const float4* s4 = (const float4*)src;
    float4 a = s4[2 * i];
    float4 b = s4[2 * i + 1];
    union { unsigned short h[8]; uint4 v; } r;
    r.h[0] = f2bf_rne(a.x); r.h[1] = f2bf_rne(a.y);
    r.h[2] = f2bf_rne(a.z); r.h[3] = f2bf_rne(a.w);
    r.h[4] = f2bf_rne(b.x); r.h[5] = f2bf_rne(b.y);
    r.h[6] = f2bf_rne(b.z); r.h[7] = f2bf_rne(b.w);
    ((uint4*)dst)[i] = r.v;
}

// ---------- async global->LDS, 16B per lane (dest is wave-uniform base + lane*16) ----------
__device__ __forceinline__ void gld_lds16(const unsigned short* g, unsigned short* l) {
    __builtin_amdgcn_global_load_lds(
        (const __attribute__((address_space(1))) void*)g,
        (__attribute__((address_space(3))) void*)l, 16, 0, 0);
}

#define BAR()   __builtin_amdgcn_s_barrier()
#define LGKM0() asm volatile("s_waitcnt lgkmcnt(0)" ::: "memory")
#define VMC4()  asm volatile("s_waitcnt vmcnt(4)" ::: "memory")
#define PRIO1() __builtin_amdgcn_s_setprio(1)
#define PRIO0() __builtin_amdgcn_s_setprio(0)

// ======================================================================
// 256x256 tile, BK=64, 512 threads (8 waves: 2 warp_m x 4 warp_n), 8-phase
// schedule with counted vmcnt. LDS 128 KiB:
//   buf{0,1} x { A: 2 halves of 128x64 bf16, B: 2 halves } ; half = 16 KiB.
// XOR swizzle (involution): 16B slot s within a 128B row, s ^= (row & 7),
// applied on the global SOURCE at staging (linear LDS dest for gld_lds) and
// on the ds_read address — both sides, same involution.
// out = sigmoid(decay)*H + Xb @ Wb^T + bias, written to out and out+MN.
// ======================================================================
__global__ __launch_bounds__(512, 2) void lrnn_gemm_fused(
        const unsigned short* __restrict__ Xb,
        const unsigned short* __restrict__ Wb,
        const float* __restrict__ H,
        const float* __restrict__ bias,
        const float* __restrict__ decay,
        float* __restrict__ out) {
    extern __shared__ char smem_raw[];
    unsigned short* lds = (unsigned short*)smem_raw;

    const int tid  = threadIdx.x;
    const int wave = tid >> 6;
    const int lane = tid & 63;
    const int l16  = lane & 15;
    const int q    = lane >> 4;
    const int l7   = lane & 7;
    const int wm   = wave >> 2;     // 0..1 : owns A rows [wm*128, +128)
    const int wn   = wave & 3;      // 0..3 : owns B cols [wn*64, +64)

    const int row0 = blockIdx.y * 256;
    const int col0 = blockIdx.x * 256;

    // Staging: half-tile = 128 rows x 64 bf16 = 1024 chunks of 16B.
    // Thread's chunks: tid and 512+tid. Source slot pre-swizzled: s ^= row&7.
    const int r0c = tid >> 3,      s0c = (tid & 7) ^ (r0c & 7);
    const int c1  = 512 + tid;
    const int r1c = c1 >> 3,       s1c = (c1 & 7) ^ (r1c & 7);
    const size_t off0 = (size_t)r0c * K_DIM + s0c * 8;   // elements
    const size_t off1 = (size_t)r1c * K_DIM + s1c * 8;
    const int stl0 = wave * 512;           // LDS dest (shorts), wave-uniform
    const int stl1 = 4096 + wave * 512;

    const unsigned short* Xg = Xb + (size_t)row0 * K_DIM;
    const unsigned short* Wg = Wb + (size_t)col0 * K_DIM;
    const size_t hstride = (size_t)128 * K_DIM;

    // Fragment read offsets (shorts) within a 128x64 half:
    // row rh = sub*16 + l16, slot = (q + 4*k32) ^ (rh&7) = (q+4k) ^ l7
    int roF[4][2];
#pragma unroll
    for (int i_ = 0; i_ < 4; ++i_)
#pragma unroll
        for (int k_ = 0; k_ < 2; ++k_)
            roF[i_][k_] = (i_ * 16 + l16) * 64 + (((q + 4 * k_) ^ l7) * 8);

    const unsigned short* rdA = lds + wm * 8192;                    // + buf*32768 + qi*4096
    const unsigned short* rdB = lds + 16384 + (wn >> 1) * 8192 + (wn & 1) * 4096; // + buf*32768 + qj*2048

    f32x4 acc[8][4] = {};
    bf16x8 a[4][2], b[2][2];

#define STAGE_A(buf, h, t) do { \
    unsigned short* lb_ = lds + (buf) * 32768 + (h) * 8192; \
    const unsigned short* gs_ = Xg + (size_t)(h) * hstride + (size_t)(t) * 64; \
    gld_lds16(gs_ + off0, lb_ + stl0); \
    gld_lds16(gs_ + off1, lb_ + stl1); } while (0)

#define STAGE_B(buf, h, t) do { \
    unsigned short* lb_ = lds + (buf) * 32768 + 16384 + (h) * 8192; \
    const unsigned short* gs_ = Wg + (size_t)(h) * hstride + (size_t)(t) * 64; \
    gld_lds16(gs_ + off0, lb_ + stl0); \
    gld_lds16(gs_ + off1, lb_ + stl1); } while (0)

#define LOAD_A(buf, qi) do { \
    const unsigned short* p_ = rdA + (buf) * 32768 + (qi) * 4096; \
    _Pragma("unroll") for (int i_ = 0; i_ < 4; ++i_) \
    _Pragma("unroll") for (int k_ = 0; k_ < 2; ++k_) \
        a[i_][k_] = *(const bf16x8*)(p_ + roF[i_][k_]); } while (0)

#define LOAD_B(buf, qj) do { \
    const unsigned short* p_ = rdB + (buf) * 32768 + (qj) * 2048; \
    _Pragma("unroll") for (int j_ = 0; j_ < 2; ++j_) \
    _Pragma("unroll") for (int k_ = 0; k_ < 2; ++k_) \
        b[j_][k_] = *(const bf16x8*)(p_ + roF[j_][k_]); } while (0)

#define MFMA_Q(qi, qj) do { \
    _Pragma("unroll") for (int i_ = 0; i_ < 4; ++i_) \
    _Pragma("unroll") for (int j_ = 0; j_ < 2; ++j_) \
    _Pragma("unroll") for (int k_ = 0; k_ < 2; ++k_) \
        acc[(qi)*4 + i_][(qj)*2 + j_] = __builtin_amdgcn_mfma_f32_16x16x32_bf16( \
            a[i_][k_], b[j_][k_], acc[(qi)*4 + i_][(qj)*2 + j_], 0, 0, 0); } while (0)

    // ---- prologue: buf0 <- tile0 (all 4 halves); buf1 <- tile1 A halves ----
    STAGE_A(0, 0, 0); STAGE_A(0, 1, 0); STAGE_B(0, 0, 0); STAGE_B(0, 1, 0);
    STAGE_A(1, 0, 1); STAGE_A(1, 1, 1);
    VMC4();             // drain buf0's 8 loads; leave buf1.A's 4 in flight
    BAR();

    // ---- main loop: 16 iterations x 2 K-tiles (NT = 32) ----
#pragma unroll 1
    for (int it = 0; it < 16; ++it) {
        const int t1 = 2 * it + 1;
        const int u0 = (2 * it + 2) & 31;   // wrap on last iter: redundant but safe
        const int u1 = (2 * it + 3) & 31;

        // P1: Q(0,0) buf0 | stage buf1.B0,B1 (tile t1)
        LOAD_A(0, 0); LOAD_B(0, 0);
        STAGE_B(1, 0, t1); STAGE_B(1, 1, t1);
        BAR(); LGKM0();
        PRIO1(); MFMA_Q(0, 0); PRIO0();
        BAR();
        // P2: Q(0,1) buf0
        LOAD_B(0, 1);
        BAR(); LGKM0();
        PRIO1(); MFMA_Q(0, 1); PRIO0();
        BAR();
        // P3: Q(1,1) buf0
        LOAD_A(0, 1);
        BAR(); LGKM0();
        PRIO1(); MFMA_Q(1, 1); PRIO0();
        BAR();
        // P4: Q(1,0) buf0 | stage buf0.A0,A1 (tile u0) | vmcnt(4)
        LOAD_B(0, 0);
        STAGE_A(0, 0, u0); STAGE_A(0, 1, u0);
        VMC4();          // drains P8-prev buf1.A + P1 buf1.B -> buf1 ready for P5
        BAR(); LGKM0();
        PRIO1(); MFMA_Q(1, 0); PRIO0();
        BAR();
        // P5: Q(0,0) buf1 | stage buf0.B0,B1 (tile u0)
        LOAD_A(1, 0); LOAD_B(1, 0);
        STAGE_B(0, 0, u0); STAGE_B(0, 1, u0);
        BAR(); LGKM0();
        PRIO1(); MFMA_Q(0, 0); PRIO0();
        BAR();
        // P6: Q(0,1) buf1
        LOAD_B(1, 1);
        BAR(); LGKM0();
        PRIO1(); MFMA_Q(0, 1); PRIO0();
        BAR();
        // P7: Q(1,1) buf1
        LOAD_A(1, 1);
        BAR(); LGKM0();
        PRIO1(); MFMA_Q(1, 1); PRIO0();
        BAR();
        // P8: Q(1,0) buf1 | stage buf1.A0,A1 (tile u1) | vmcnt(4)
        LOAD_B(1, 0);
        STAGE_A(1, 0, u1); STAGE_A(1, 1, u1);
        VMC4();          // drains P4 buf0.A + P5 buf0.B -> buf0 ready for next P1
        BAR(); LGKM0();
        PRIO1(); MFMA_Q(1, 0); PRIO0();
        BAR();
    }

    asm volatile("s_waitcnt vmcnt(0)" ::: "memory");   // drain trailing stages

    // ---- epilogue: C/D 16x16 layout: col = l16, row = q*4 + r ----
    const size_t MN = (size_t)M_BATCH * N_DIM;
#pragma unroll
    for (int j = 0; j < 4; ++j) {
        const int col = col0 + wn * 64 + j * 16 + l16;
        const float al = 1.0f / (1.0f + __expf(-decay[col]));
        const float bb = bias[col];
#pragma unroll
        for (int i = 0; i < 8; ++i) {
            const int row = row0 + wm * 128 + i * 16 + q * 4;
#pragma unroll
            for (int r = 0; r < 4; ++r) {
                size_t idx = (size_t)(row + r) * N_DIM + col;
                float v = al * H[idx] + acc[i][j][r] + bb;
                out[idx] = v;
                out[MN + idx] = v;
            }
        }
    }

#undef STAGE_A
#undef STAGE_B
#undef LOAD_A
#undef LOAD_B
#undef MFMA_Q
}

extern "C" void kernel_launch(void* const* d_in, const int* in_sizes, int n_in,
                              void* d_out, int out_size, void* d_ws, size_t ws_size,
                              hipStream_t stream) {
    const float* x     = (const float*)d_in[0];
    const float* h     = (const float*)d_in[1];
    const float* W     = (const float*)d_in[2];
    const float* b     = (const float*)d_in[3];
    const float* decay = (const float*)d_in[4];
    float* out = (float*)d_out;

    unsigned short* xb = (unsigned short*)d_ws;                 // [M,K] bf16: 64 MiB
    unsigned short* wb = xb + (size_t)M_BATCH * K_DIM;          // [N,K] bf16:  8 MiB

    static bool cfg = false;
    if (!cfg) {
        hipFuncSetAttribute((const void*)lrnn_gemm_fused,
                            hipFuncAttributeMaxDynamicSharedMemorySize, 131072);
        cfg = true;
    }

    const int n8x = M_BATCH * K_DIM / 8;
    cvt_f32_bf16_x8<<<n8x / 256, 256, 0, stream>>>(x, xb, n8x);
    const int n8w = N_DIM * K_DIM / 8;
    cvt_f32_bf16_x8<<<n8w / 256, 256, 0, stream>>>(W, wb, n8w);

    dim3 grid(N_DIM / 256, M_BATCH / 256);   // (8, 64)
    lrnn_gemm_fused<<<grid, 512, 131072, stream>>>(xb, wb, h, b, decay, out);
}

// Round 3
// 597.916 us; speedup vs baseline: 1.1399x; 1.1399x over previous
//
#include <hip/hip_runtime.h>

#define M_BATCH 16384
#define N_DIM   2048
#define K_DIM   2048

typedef __attribute__((ext_vector_type(8))) short bf16x8;   // 8 bf16 = 4 VGPRs
typedef __attribute__((ext_vector_type(4))) float f32x4;

// ---------- fp32 -> bf16 (RNE) conversion, 8 elements/thread ----------
__device__ __forceinline__ unsigned short f2bf_rne(float f) {
    union { float f; unsigned int u; } v; v.f = f;
    unsigned int r = v.u + 0x7fffu + ((v.u >> 16) & 1u);
    return (unsigned short)(r >> 16);
}

__global__ __launch_bounds__(256) void cvt_f32_bf16_x8(
        const float* __restrict__ src, unsigned short* __restrict__ dst, int n8) {
    int i = blockIdx.x * blockDim.x + threadIdx.x;
    if (i >= n8) return;
    const float4* s4 = (const float4*)src;
    float4 a = s4[2 * i];
    float4 b = s4[2 * i + 1];
    union { unsigned short h[8]; uint4 v; } r;
    r.h[0] = f2bf_rne(a.x); r.h[1] = f2bf_rne(a.y);
    r.h[2] = f2bf_rne(a.z); r.h[3] = f2bf_rne(a.w);
    r.h[4] = f2bf_rne(b.x); r.h[5] = f2bf_rne(b.y);
    r.h[6] = f2bf_rne(b.z); r.h[7] = f2bf_rne(b.w);
    ((uint4*)dst)[i] = r.v;
}

// ---------- async global->LDS, 16B per lane (dest wave-uniform base + lane*16) ----------
__device__ __forceinline__ void gld_lds16(const unsigned short* g, unsigned short* l) {
    __builtin_amdgcn_global_load_lds(
        (const __attribute__((address_space(1))) void*)g,
        (__attribute__((address_space(3))) void*)l, 16, 0, 0);
}

#define BAR()   __builtin_amdgcn_s_barrier()
#define LGKM0() asm volatile("s_waitcnt lgkmcnt(0)" ::: "memory")
#define VMC0()  asm volatile("s_waitcnt vmcnt(0)" ::: "memory")
#define PRIO1() __builtin_amdgcn_s_setprio(1)
#define PRIO0() __builtin_amdgcn_s_setprio(0)

// ======================================================================
// 128x128 tile, BK=64, 256 threads (4 waves, 2x2; wave tile 64x64).
// Double-buffered LDS: 2 x (A 128x64 + B 128x64) bf16 = 64 KiB (static)
//   -> 2 blocks/CU; cross-block overlap hides stage/barrier bubbles.
// Per K-tile: STAGE(next -> buf^1) ; ds_read(buf) ; lgkmcnt(0) ;
//   setprio(1) 32 MFMA setprio(0) ; vmcnt(0) ; barrier.
// XOR swizzle (involution, proven 0-conflict in round 1): 16B slot s within
// a 128B row, s ^= (row & 7) — applied on the global SOURCE (linear LDS dest
// for global_load_lds) and on the ds_read address.
// XCD swizzle (bijective, 2048 blocks % 8 == 0): each XCD gets 16 contiguous
// by-panels -> disjoint 1/8 of A per XCD-L2, A HBM-fetched once.
// out = sigmoid(decay)*H + Xb @ Wb^T + bias, written to out and out+MN.
// ======================================================================
__global__ __launch_bounds__(256, 2) void lrnn_gemm_fused(
        const unsigned short* __restrict__ Xb,
        const unsigned short* __restrict__ Wb,
        const float* __restrict__ H,
        const float* __restrict__ bias,
        const float* __restrict__ decay,
        float* __restrict__ out) {
    __shared__ __align__(16) unsigned short lds[32768];  // [2][8192] A, [2][8192] B

    const int tid  = threadIdx.x;
    const int wave = tid >> 6;
    const int lane = tid & 63;
    const int l16  = lane & 15;
    const int q    = lane >> 4;
    const int l7   = lane & 7;
    const int wr   = wave >> 1;     // 0..1: rows [wr*64, +64)
    const int wc   = wave & 1;      // 0..1: cols [wc*64, +64)

    // ---- XCD-aware block swizzle ----
    const int wid = blockIdx.y * 16 + blockIdx.x;        // 0..2047
    const int nid = (wid & 7) * 256 + (wid >> 3);
    const int bx  = nid & 15;
    const int by  = nid >> 4;
    const int row0 = by * 128;
    const int col0 = bx * 128;

    // ---- staging: per buffer, A = 128x64 bf16 = 1024 16B-chunks; B same.
    // Thread t handles chunks t+256*i (i=0..3); each wave's 64 chunks are a
    // contiguous run -> linear LDS dest (wave-uniform base + lane*16).
    // Global source slot pre-swizzled: s = (c&7) ^ (row&7).
    const unsigned short* gA[4];
    const unsigned short* gB[4];
    int ldst[4];
#pragma unroll
    for (int i = 0; i < 4; ++i) {
        const int c = tid + 256 * i;
        const int r = c >> 3;
        const int s = (c & 7) ^ (r & 7);
        gA[i] = Xb + (size_t)(row0 + r) * K_DIM + s * 8;
        gB[i] = Wb + (size_t)(col0 + r) * K_DIM + s * 8;
        ldst[i] = wave * 512 + i * 2048;      // shorts; wave-uniform
    }

    // ---- fragment ds_read offsets (shorts) within a 128x64 region:
    // row = sub*16 + l16 (row&7 == l7), global 16B slot (q+4*kk), read slot
    // = (q+4*kk) ^ l7  (same involution as the staged source).
    int fo[4][2];
#pragma unroll
    for (int i = 0; i < 4; ++i)
#pragma unroll
        for (int kk = 0; kk < 2; ++kk)
            fo[i][kk] = (i * 16 + l16) * 64 + (((q + 4 * kk) ^ l7) * 8);

    const int aBase = wr * 4096;            // + buf*8192
    const int bBase = 16384 + wc * 4096;    // + buf*8192

    f32x4 acc[4][4] = {};
    bf16x8 a[4][2], b[4][2];

#define STAGE(buf, t) do { \
    const int k0_ = (t) * 64; \
    unsigned short* la_ = lds + (buf) * 8192; \
    unsigned short* lb_ = lds + 16384 + (buf) * 8192; \
    _Pragma("unroll") for (int i_ = 0; i_ < 4; ++i_) gld_lds16(gA[i_] + k0_, la_ + ldst[i_]); \
    _Pragma("unroll") for (int i_ = 0; i_ < 4; ++i_) gld_lds16(gB[i_] + k0_, lb_ + ldst[i_]); \
    } while (0)

#define LOAD(buf) do { \
    const unsigned short* pa_ = lds + (buf) * 8192 + aBase; \
    const unsigned short* pb_ = lds + (buf) * 8192 + bBase; \
    _Pragma("unroll") for (int i_ = 0; i_ < 4; ++i_) \
    _Pragma("unroll") for (int k_ = 0; k_ < 2; ++k_) { \
        a[i_][k_] = *(const bf16x8*)(pa_ + fo[i_][k_]); \
        b[i_][k_] = *(const bf16x8*)(pb_ + fo[i_][k_]); } \
    } while (0)

#define MFMA_ALL() do { \
    _Pragma("unroll") for (int i_ = 0; i_ < 4; ++i_) \
    _Pragma("unroll") for (int j_ = 0; j_ < 4; ++j_) \
    _Pragma("unroll") for (int k_ = 0; k_ < 2; ++k_) \
        acc[i_][j_] = __builtin_amdgcn_mfma_f32_16x16x32_bf16( \
            a[i_][k_], b[j_][k_], acc[i_][j_], 0, 0, 0); \
    } while (0)

    // ---- prologue: tile 0 -> buf0 ----
    STAGE(0, 0);
    VMC0();
    BAR();

    // ---- main loop: 32 K-tiles, unrolled x2 so buffer index is static ----
#pragma unroll 1
    for (int it = 0; it < 16; ++it) {
        // even tile 2*it (buf0); prefetch tile 2*it+1 -> buf1
        STAGE(1, 2 * it + 1);
        LOAD(0);
        LGKM0();
        PRIO1(); MFMA_ALL(); PRIO0();
        VMC0();          // buf1 staged (latency hidden under reads+MFMA above)
        BAR();
        // odd tile 2*it+1 (buf1); prefetch tile 2*it+2 -> buf0
        if (it < 15) STAGE(0, 2 * it + 2);
        LOAD(1);
        LGKM0();
        PRIO1(); MFMA_ALL(); PRIO0();
        VMC0();
        BAR();
    }

    // ---- epilogue: C/D 16x16 layout: col = l16, row = q*4 + r ----
    const size_t MN = (size_t)M_BATCH * N_DIM;
#pragma unroll
    for (int j = 0; j < 4; ++j) {
        const int col = col0 + wc * 64 + j * 16 + l16;
        const float al = 1.0f / (1.0f + __expf(-decay[col]));
        const float bb = bias[col];
#pragma unroll
        for (int i = 0; i < 4; ++i) {
            const int row = row0 + wr * 64 + i * 16 + q * 4;
#pragma unroll
            for (int r = 0; r < 4; ++r) {
                size_t idx = (size_t)(row + r) * N_DIM + col;
                float v = al * H[idx] + acc[i][j][r] + bb;
                out[idx] = v;
                out[MN + idx] = v;
            }
        }
    }

#undef STAGE
#undef LOAD
#undef MFMA_ALL
}

extern "C" void kernel_launch(void* const* d_in, const int* in_sizes, int n_in,
                              void* d_out, int out_size, void* d_ws, size_t ws_size,
                              hipStream_t stream) {
    const float* x     = (const float*)d_in[0];
    const float* h     = (const float*)d_in[1];
    const float* W     = (const float*)d_in[2];
    const float* b     = (const float*)d_in[3];
    const float* decay = (const float*)d_in[4];
    float* out = (float*)d_out;

    unsigned short* xb = (unsigned short*)d_ws;                 // [M,K] bf16: 64 MiB
    unsigned short* wb = xb + (size_t)M_BATCH * K_DIM;          // [N,K] bf16:  8 MiB

    const int n8x = M_BATCH * K_DIM / 8;
    cvt_f32_bf16_x8<<<n8x / 256, 256, 0, stream>>>(x, xb, n8x);
    const int n8w = N_DIM * K_DIM / 8;
    cvt_f32_bf16_x8<<<n8w / 256, 256, 0, stream>>>(W, wb, n8w);

    dim3 grid(N_DIM / 128, M_BATCH / 128);   // (16, 128)
    lrnn_gemm_fused<<<grid, 256, 0, stream>>>(xb, wb, h, b, decay, out);
}